// Round 1
// baseline (1441.110 us; speedup 1.0000x reference)
//
#include <hip/hip_runtime.h>
#include <math.h>

// Problem constants
#define B_SZ   16
#define H_SZ   1024
#define W_SZ   1024
#define NPIX   (H_SZ * W_SZ)          // 1048576 per batch
#define K_THR  104857u                 // int((1-0.9)*2^20) = 104857, k-th largest
#define TOPK   5

// ---------- helpers ----------

// Monotone map: float bits -> sortable unsigned (larger float => larger uint)
__device__ __forceinline__ unsigned sort32(unsigned u) {
    return (u & 0x80000000u) ? ~u : (u | 0x80000000u);
}
__device__ __forceinline__ float unsort32(unsigned u) {
    unsigned v = (u & 0x80000000u) ? (u & 0x7FFFFFFFu) : ~u;
    return __uint_as_float(v);
}

// Insert key into descending-sorted 5-array (t[0] largest)
__device__ __forceinline__ void insert5(unsigned long long t[5], unsigned long long key) {
    if (key <= t[4]) return;
    t[4] = key;
#pragma unroll
    for (int i = 4; i > 0; --i) {
        if (t[i] > t[i - 1]) {
            unsigned long long tmp = t[i - 1];
            t[i - 1] = t[i];
            t[i] = tmp;
        }
    }
}

// Merge descending-sorted a[5] with descending-sorted b[5] (from LDS), keep top-5 in a.
__device__ __forceinline__ void merge5(unsigned long long a[5], const unsigned long long* b) {
    unsigned long long o[5];
    int i = 0, j = 0;
#pragma unroll
    for (int k = 0; k < 5; ++k) {       // i+j == k <= 4, so no OOB reads
        unsigned long long av = a[i], bv = b[j];
        if (av >= bv) { o[k] = av; ++i; } else { o[k] = bv; ++j; }
    }
#pragma unroll
    for (int k = 0; k < 5; ++k) a[k] = o[k];
}

// ---------- kernels ----------

__global__ __launch_bounds__(256) void zero_kernel(unsigned* p, int n) {
    int i = blockIdx.x * 256 + threadIdx.x;
    if (i < n) p[i] = 0;
}

// Level-1 histogram: top 12 bits of sortable uint, LDS-privatized.
// Grid: 4096 blocks x 256 threads x 16 elems (4x uint4) = 16M elements.
__global__ __launch_bounds__(256) void hist1_kernel(const unsigned* __restrict__ in,
                                                    unsigned* __restrict__ hist) {
    __shared__ unsigned lh[4096];
    for (int i = threadIdx.x; i < 4096; i += 256) lh[i] = 0;
    __syncthreads();

    size_t blockbase = (size_t)blockIdx.x * 4096;
#pragma unroll
    for (int i = 0; i < 4; ++i) {
        uint4 v = *(const uint4*)(in + blockbase + (size_t)(i * 256 + threadIdx.x) * 4);
        atomicAdd(&lh[sort32(v.x) >> 20], 1u);
        atomicAdd(&lh[sort32(v.y) >> 20], 1u);
        atomicAdd(&lh[sort32(v.z) >> 20], 1u);
        atomicAdd(&lh[sort32(v.w) >> 20], 1u);
    }
    __syncthreads();

    int b = blockIdx.x >> 8;                   // 256 blocks per batch
    unsigned* h = hist + (b << 12);
    for (int i = threadIdx.x; i < 4096; i += 256) {
        unsigned c = lh[i];
        if (c) atomicAdd(&h[i], c);
    }
}

// Filtered histogram for levels 2/3: count elements whose sortable bits match
// prefix at prefix_shift; bin = (s >> bin_shift) & bin_mask. Sparse -> global atomics.
__global__ __launch_bounds__(256) void hist_filter_kernel(const unsigned* __restrict__ in,
                                                          unsigned* __restrict__ hist, int nbins,
                                                          const unsigned* __restrict__ prefix,
                                                          int prefix_shift, int bin_shift,
                                                          unsigned bin_mask) {
    int b = blockIdx.x >> 8;
    unsigned pfx = prefix[b];
    unsigned* h = hist + b * nbins;
    size_t blockbase = (size_t)blockIdx.x * 4096;
#pragma unroll
    for (int i = 0; i < 4; ++i) {
        uint4 v = *(const uint4*)(in + blockbase + (size_t)(i * 256 + threadIdx.x) * 4);
        unsigned s;
        s = sort32(v.x); if ((s >> prefix_shift) == pfx) atomicAdd(&h[(s >> bin_shift) & bin_mask], 1u);
        s = sort32(v.y); if ((s >> prefix_shift) == pfx) atomicAdd(&h[(s >> bin_shift) & bin_mask], 1u);
        s = sort32(v.z); if ((s >> prefix_shift) == pfx) atomicAdd(&h[(s >> bin_shift) & bin_mask], 1u);
        s = sort32(v.w); if ((s >> prefix_shift) == pfx) atomicAdd(&h[(s >> bin_shift) & bin_mask], 1u);
    }
}

// Per-batch radix-select step: scan bins from top, find bin containing rank k.
// rank_in == null -> k = K_THR. prefix_out = (prefix_in << prefix_shift) | bin.
// thr_out != null (last level): prefix is the full 32-bit sortable value -> decode.
__global__ void select_kernel(const unsigned* __restrict__ hist, int nbins,
                              const unsigned* __restrict__ rank_in,
                              unsigned* __restrict__ rank_out,
                              const unsigned* __restrict__ prefix_in, int prefix_shift,
                              unsigned* __restrict__ prefix_out,
                              float* __restrict__ thr_out) {
    int b = threadIdx.x;
    if (b >= B_SZ) return;
    const unsigned* h = hist + b * nbins;
    unsigned k = rank_in ? rank_in[b] : K_THR;
    unsigned c = 0;
    int sel = 0;
    for (int bin = nbins - 1; bin >= 0; --bin) {
        unsigned cnt = h[bin];
        if (c + cnt >= k) { sel = bin; break; }
        c += cnt;
    }
    unsigned pfx = prefix_in ? ((prefix_in[b] << prefix_shift) | (unsigned)sel) : (unsigned)sel;
    if (prefix_out) prefix_out[b] = pfx;
    if (rank_out)   rank_out[b]   = k - c;
    if (thr_out)    thr_out[b]    = unsort32(pfx);
}

// Peak detection: one block per image row. Each thread: 4 consecutive pixels.
// Peak iff v > thr and v >= all neighbors in 9x9 clipped window.
// Key = (sortable(v) << 32) | ~idx  (value desc, index asc). Sentinel 0 < any real key.
__global__ __launch_bounds__(256) void peak_kernel(const float* __restrict__ in,
                                                   const float* __restrict__ thr_arr,
                                                   unsigned long long* __restrict__ blocktop,
                                                   unsigned long long* __restrict__ blockmax) {
    int bid = blockIdx.x;              // 0..16383
    int b = bid >> 10;
    int y = bid & 1023;
    int tid = threadIdx.x;
    const float* img = in + ((size_t)b << 20);
    int x0 = tid * 4;

    float4 v4 = *(const float4*)(img + y * W_SZ + x0);
    float thr = thr_arr[b];

    unsigned long long t[5] = {0, 0, 0, 0, 0};
    unsigned long long mk = 0;
    float vals[4] = {v4.x, v4.y, v4.z, v4.w};

#pragma unroll
    for (int j = 0; j < 4; ++j) {
        float val = vals[j];
        int x = x0 + j;
        unsigned idx = (unsigned)(y * W_SZ + x);
        unsigned long long key =
            ((unsigned long long)sort32(__float_as_uint(val)) << 32) | (unsigned)(~idx);
        if (key > mk) mk = key;
        if (val > thr) {
            bool peak = true;
            for (int dy = -4; dy <= 4 && peak; ++dy) {
                int yy = y + dy;
                if ((unsigned)yy >= (unsigned)H_SZ) continue;
                const float* row = img + yy * W_SZ;
                for (int dx = -4; dx <= 4; ++dx) {
                    int xx = x + dx;
                    if ((unsigned)xx >= (unsigned)W_SZ) continue;
                    if ((dy | dx) == 0) continue;     // skip self
                    if (row[xx] > val) { peak = false; break; }
                }
            }
            if (peak) insert5(t, key);
        }
    }

    // Block reductions: top-5 merge tree + max.
    __shared__ unsigned long long sh5[256 * 5];
    __shared__ unsigned long long shm[256];
#pragma unroll
    for (int k = 0; k < 5; ++k) sh5[tid * 5 + k] = t[k];
    shm[tid] = mk;
    __syncthreads();
    for (int s = 128; s > 0; s >>= 1) {
        if (tid < s) {
            unsigned long long a[5];
#pragma unroll
            for (int k = 0; k < 5; ++k) a[k] = sh5[tid * 5 + k];
            merge5(a, &sh5[(tid + s) * 5]);
#pragma unroll
            for (int k = 0; k < 5; ++k) sh5[tid * 5 + k] = a[k];
            if (shm[tid + s] > shm[tid]) shm[tid] = shm[tid + s];
        }
        __syncthreads();
    }
    if (tid == 0) {
#pragma unroll
        for (int k = 0; k < 5; ++k) blocktop[(size_t)bid * 5 + k] = sh5[k];
        blockmax[bid] = shm[0];
    }
}

// Final: one block per batch. Merge 1024 block top-5 lists + 1024 block maxes,
// then reference epilogue.
__global__ __launch_bounds__(256) void final_kernel(const unsigned long long* __restrict__ blocktop,
                                                    const unsigned long long* __restrict__ blockmax,
                                                    float* __restrict__ out) {
    int b = blockIdx.x;
    int tid = threadIdx.x;
    const unsigned long long* bt = blocktop + (size_t)b * 5120;
    const unsigned long long* bm = blockmax + (size_t)b * 1024;

    unsigned long long t[5] = {0, 0, 0, 0, 0};
    for (int i = tid; i < 5120; i += 256) insert5(t, bt[i]);
    unsigned long long mk = 0;
    for (int i = tid; i < 1024; i += 256) {
        unsigned long long v = bm[i];
        if (v > mk) mk = v;
    }

    __shared__ unsigned long long sh5[256 * 5];
    __shared__ unsigned long long shm[256];
#pragma unroll
    for (int k = 0; k < 5; ++k) sh5[tid * 5 + k] = t[k];
    shm[tid] = mk;
    __syncthreads();
    for (int s = 128; s > 0; s >>= 1) {
        if (tid < s) {
            unsigned long long a[5];
#pragma unroll
            for (int k = 0; k < 5; ++k) a[k] = sh5[tid * 5 + k];
            merge5(a, &sh5[(tid + s) * 5]);
#pragma unroll
            for (int k = 0; k < 5; ++k) sh5[tid * 5 + k] = a[k];
            if (shm[tid + s] > shm[tid]) shm[tid] = shm[tid + s];
        }
        __syncthreads();
    }

    if (tid == 0) {
        float topv[5], xs[5], ys[5];
        bool hp[5];
#pragma unroll
        for (int j = 0; j < 5; ++j) {
            unsigned long long key = sh5[j];
            hp[j] = (key != 0ull);
            if (hp[j]) {
                topv[j] = unsort32((unsigned)(key >> 32));
                unsigned idx = ~((unsigned)key);
                xs[j] = (float)(idx & (W_SZ - 1));
                ys[j] = (float)(idx >> 10);
            } else {
                topv[j] = -INFINITY;
                xs[j] = 0.0f;
                ys[j] = 0.0f;
            }
        }
        if (!hp[0]) {                 // fallback: global argmax (first occurrence)
            unsigned idx = ~((unsigned)shm[0]);
            xs[0] = (float)(idx & (W_SZ - 1));
            ys[0] = (float)(idx >> 10);
        }
        float pm = topv[0];
        int nv = 0;
#pragma unroll
        for (int j = 0; j < 5; ++j) {
            bool valid = (topv[j] >= pm * 0.5f) && hp[j];
            nv += valid ? 1 : 0;
        }
        if (nv < 1) nv = 1;
#pragma unroll
        for (int j = 0; j < 5; ++j) {
            bool keep = (j < nv);
            out[b * 10 + j * 2 + 0] = keep ? xs[j] : -1.0f;
            out[b * 10 + j * 2 + 1] = keep ? ys[j] : -1.0f;
            out[160 + b * 5 + j]    = keep ? 1.0f : -1.0f;
        }
    }
}

// ---------- launch ----------

extern "C" void kernel_launch(void* const* d_in, const int* in_sizes, int n_in,
                              void* d_out, int out_size, void* d_ws, size_t ws_size,
                              hipStream_t stream) {
    const float* in = (const float*)d_in[0];
    float* out = (float*)d_out;

    // Workspace layout (u64 arrays first for alignment):
    unsigned long long* blocktop = (unsigned long long*)d_ws;        // 16*1024*5
    unsigned long long* blockmax = blocktop + 16384 * 5;             // 16*1024
    unsigned* hist1 = (unsigned*)(blockmax + 16384);                 // 16*4096
    unsigned* hist2 = hist1 + 16 * 4096;                             // 16*4096
    unsigned* hist3 = hist2 + 16 * 4096;                             // 16*256
    unsigned* rank1 = hist3 + 16 * 256;                              // 16
    unsigned* rank2 = rank1 + 16;                                    // 16
    unsigned* pfx1  = rank2 + 16;                                    // 16
    unsigned* pfx2  = pfx1 + 16;                                     // 16
    float*    thr   = (float*)(pfx2 + 16);                           // 16

    // Zero the three histogram arrays: 16*4096 + 16*4096 + 16*256 = 135168 words.
    zero_kernel<<<528, 256, 0, stream>>>(hist1, 135168);

    // Exact per-batch k-th largest (dyn_thr) via 12+12+8-bit radix select.
    hist1_kernel<<<4096, 256, 0, stream>>>((const unsigned*)in, hist1);
    select_kernel<<<1, 64, 0, stream>>>(hist1, 4096, nullptr, rank1, nullptr, 0, pfx1, nullptr);
    hist_filter_kernel<<<4096, 256, 0, stream>>>((const unsigned*)in, hist2, 4096, pfx1, 20, 8, 0xFFFu);
    select_kernel<<<1, 64, 0, stream>>>(hist2, 4096, rank1, rank2, pfx1, 12, pfx2, nullptr);
    hist_filter_kernel<<<4096, 256, 0, stream>>>((const unsigned*)in, hist3, 256, pfx2, 8, 0, 0xFFu);
    select_kernel<<<1, 64, 0, stream>>>(hist3, 256, rank2, nullptr, pfx2, 8, nullptr, thr);

    // Peak detection + per-block top-5 / max.
    peak_kernel<<<16384, 256, 0, stream>>>(in, thr, blocktop, blockmax);

    // Final per-batch reduction + epilogue.
    final_kernel<<<16, 256, 0, stream>>>(blocktop, blockmax, out);
}

// Round 2
// 470.854 us; speedup vs baseline: 3.0606x; 3.0606x over previous
//
#include <hip/hip_runtime.h>
#include <math.h>

// Problem constants
#define B_SZ   16
#define H_SZ   1024
#define W_SZ   1024
#define K_THR  104857u                 // int((1-0.9)*2^20), rank from top
#define TOPK   5

// Tile geometry for the fused pass
#define TW 64
#define TH 32
#define HALO 4
#define SW (TW + 2*HALO)   // 72 staged width
#define SH (TH + 2*HALO)   // 40 staged height

#define EXT_CAP  32768     // per-batch capacity for selected-bin values (~23k expected)
#define CAND_CAP 16384     // per-batch capacity for local-max candidates (~13k expected)
#define CAND_LDS 128       // per-block candidate staging (expect ~25)

// ---------- helpers ----------

__device__ __forceinline__ unsigned sort32(unsigned u) {
    return (u & 0x80000000u) ? ~u : (u | 0x80000000u);
}
__device__ __forceinline__ float unsort32(unsigned u) {
    unsigned v = (u & 0x80000000u) ? (u & 0x7FFFFFFFu) : ~u;
    return __uint_as_float(v);
}

__device__ __forceinline__ void insert5(unsigned long long t[5], unsigned long long key) {
    if (key <= t[4]) return;
    t[4] = key;
#pragma unroll
    for (int i = 4; i > 0; --i) {
        if (t[i] > t[i - 1]) {
            unsigned long long tmp = t[i - 1];
            t[i - 1] = t[i];
            t[i] = tmp;
        }
    }
}

__device__ __forceinline__ void merge5(unsigned long long a[5], const unsigned long long* b) {
    unsigned long long o[5];
    int i = 0, j = 0;
#pragma unroll
    for (int k = 0; k < 5; ++k) {
        unsigned long long av = a[i], bv = b[j];
        if (av >= bv) { o[k] = av; ++i; } else { o[k] = bv; ++j; }
    }
#pragma unroll
    for (int k = 0; k < 5; ++k) a[k] = o[k];
}

// ---------- kernels ----------

__global__ __launch_bounds__(256) void zero_kernel(unsigned* p, int n) {
    int i = blockIdx.x * 256 + threadIdx.x;
    if (i < n) p[i] = 0;
}

// Fused single pass: separable 9x9 local-max (candidates), 4096-bin value
// histogram (top 12 bits of sortable float), global argmax key.
// Grid: 16 batches * 512 tiles (16x32 of 64x32) = 8192 blocks, 256 threads.
__global__ __launch_bounds__(256) void main_kernel(const float* __restrict__ in,
                                                   unsigned* __restrict__ hist,
                                                   unsigned long long* __restrict__ cands,
                                                   unsigned* __restrict__ candcnt,
                                                   unsigned long long* __restrict__ batchmax) {
    __shared__ float stile[SH * SW];          // 40x72 staged tile (+halo)
    __shared__ float hbuf[SH * TW];           // 40x64 horizontal 9-max
    __shared__ unsigned lh[4096];             // local histogram
    __shared__ unsigned long long lc[CAND_LDS];
    __shared__ unsigned lcnt, lbase;
    __shared__ unsigned long long wmax[4];

    int bid = blockIdx.x;
    int b   = bid >> 9;                       // batch
    int t   = bid & 511;
    int x0  = (t & 15) << 6;                  // tile origin
    int y0  = (t >> 4) << 5;
    int tid = threadIdx.x;
    const float* img = in + ((size_t)b << 20);

    // Stage tile + halo (out-of-image -> -inf)
    for (int i = tid; i < SH * SW; i += 256) {
        int r = i / SW, c = i % SW;
        int gy = y0 + r - HALO, gx = x0 + c - HALO;
        float v = -INFINITY;
        if ((unsigned)gy < (unsigned)H_SZ && (unsigned)gx < (unsigned)W_SZ)
            v = img[gy * W_SZ + gx];
        stile[i] = v;
    }
    for (int i = tid; i < 4096; i += 256) lh[i] = 0;
    if (tid == 0) lcnt = 0;
    __syncthreads();

    // Horizontal 9-max: 40 rows x 8 runs of 8 outputs = 320 runs.
    // hbuf[r][c] = max(stile[r][c .. c+8]) for c in 0..63.
    for (int run = tid; run < SH * 8; run += 256) {
        int r  = run >> 3;
        int c0 = (run & 7) << 3;
        const float4* p = (const float4*)&stile[r * SW + c0];
        float4 q0 = p[0], q1 = p[1], q2 = p[2], q3 = p[3];
        float a[16] = {q0.x, q0.y, q0.z, q0.w, q1.x, q1.y, q1.z, q1.w,
                       q2.x, q2.y, q2.z, q2.w, q3.x, q3.y, q3.z, q3.w};
        float S[8], P[8];
        S[7] = a[7];
#pragma unroll
        for (int i = 6; i >= 0; --i) S[i] = fmaxf(a[i], S[i + 1]);
        P[0] = a[8];
#pragma unroll
        for (int j = 1; j < 8; ++j) P[j] = fmaxf(P[j - 1], a[8 + j]);
        float o0[8];
#pragma unroll
        for (int o = 0; o < 8; ++o) o0[o] = fmaxf(S[o], P[o]);
        float4* w = (float4*)&hbuf[r * TW + c0];
        w[0] = make_float4(o0[0], o0[1], o0[2], o0[3]);
        w[1] = make_float4(o0[4], o0[5], o0[6], o0[7]);
    }
    __syncthreads();

    // Vertical 9-max + candidate test + histogram + argmax key.
    // 256 runs: col c (0..63) x row-group rg (0..3), each run 8 output rows.
    int c  = tid & 63;
    int r0 = (tid >> 6) << 3;
    float a[16];
#pragma unroll
    for (int i = 0; i < 16; ++i) a[i] = hbuf[(r0 + i) * TW + c];
    float S[8], P[8];
    S[7] = a[7];
#pragma unroll
    for (int i = 6; i >= 0; --i) S[i] = fmaxf(a[i], S[i + 1]);
    P[0] = a[8];
#pragma unroll
    for (int j = 1; j < 8; ++j) P[j] = fmaxf(P[j - 1], a[8 + j]);

    unsigned long long mymax = 0;
#pragma unroll
    for (int o = 0; o < 8; ++o) {
        int ry = r0 + o;
        float vm = fmaxf(S[o], P[o]);
        float v  = stile[(ry + HALO) * SW + (c + HALO)];
        unsigned s = sort32(__float_as_uint(v));
        atomicAdd(&lh[s >> 20], 1u);
        unsigned idx = (unsigned)(((y0 + ry) << 10) | (x0 + c));
        unsigned long long key = ((unsigned long long)s << 32) | (unsigned)(~idx);
        if (key > mymax) mymax = key;
        if (v == vm) {                         // v >= all 80 neighbors
            unsigned p = atomicAdd(&lcnt, 1u);
            if (p < CAND_LDS) lc[p] = key;
        }
    }

    // Wave-level max, then block max -> global atomicMax.
#pragma unroll
    for (int off = 32; off > 0; off >>= 1) {
        unsigned long long o = __shfl_down(mymax, off);
        if (o > mymax) mymax = o;
    }
    if ((tid & 63) == 0) wmax[tid >> 6] = mymax;
    __syncthreads();

    if (tid == 0) {
        unsigned long long m = wmax[0];
        for (int i = 1; i < 4; ++i) if (wmax[i] > m) m = wmax[i];
        atomicMax(&batchmax[b], m);
        unsigned n = lcnt; if (n > CAND_LDS) n = CAND_LDS;
        lbase = atomicAdd(&candcnt[b], n);
    }
    __syncthreads();

    // Flush histogram and candidates.
    unsigned* h = hist + (b << 12);
    for (int i = tid; i < 4096; i += 256) {
        unsigned cc = lh[i];
        if (cc) atomicAdd(&h[i], cc);
    }
    unsigned n = lcnt; if (n > CAND_LDS) n = CAND_LDS;
    unsigned base = lbase;
    for (unsigned i = tid; i < n; i += 256) {
        unsigned pos = base + i;
        if (pos < CAND_CAP) cands[(size_t)b * CAND_CAP + pos] = lc[i];
    }
}

// Level-1 select: per-batch, find 12-bit bin containing rank K_THR from top.
__global__ __launch_bounds__(256) void selbin_kernel(const unsigned* __restrict__ hist,
                                                     unsigned* __restrict__ selbin,
                                                     unsigned* __restrict__ k2v) {
    __shared__ unsigned s[256];
    int b = blockIdx.x, t = threadIdx.x;
    const unsigned* h = hist + (b << 12);
    unsigned sum = 0;
#pragma unroll
    for (int i = 0; i < 16; ++i) sum += h[t * 16 + i];
    s[t] = sum;
    __syncthreads();
    if (t == 0) {
        unsigned c = 0;
        int chunk = 0;
        for (int ch = 255; ch >= 0; --ch) {
            if (c + s[ch] >= K_THR) { chunk = ch; break; }
            c += s[ch];
        }
        int selb = chunk * 16;
        for (int bin = chunk * 16 + 15; bin >= chunk * 16; --bin) {
            unsigned cnt = h[bin];
            if (c + cnt >= K_THR) { selb = bin; break; }
            c += cnt;
        }
        selbin[b] = (unsigned)selb;
        k2v[b]    = K_THR - c;
    }
}

// Extract all values (sortable bits) whose top-12 bits == selbin, per batch.
// Grid: 4096 blocks x 256 threads x 16 elems.
__global__ __launch_bounds__(256) void extract_kernel(const unsigned* __restrict__ in,
                                                      const unsigned* __restrict__ selbin,
                                                      unsigned* __restrict__ ext,
                                                      unsigned* __restrict__ extcnt) {
    __shared__ unsigned buf[4096];
    __shared__ unsigned cnt, base;
    int b = blockIdx.x >> 8;
    unsigned sb = selbin[b];
    if (threadIdx.x == 0) cnt = 0;
    __syncthreads();
    size_t blockbase = (size_t)blockIdx.x * 4096;
#pragma unroll
    for (int i = 0; i < 4; ++i) {
        uint4 v = *(const uint4*)(in + blockbase + (size_t)(i * 256 + threadIdx.x) * 4);
        unsigned s;
        s = sort32(v.x); if ((s >> 20) == sb) buf[atomicAdd(&cnt, 1u)] = s;
        s = sort32(v.y); if ((s >> 20) == sb) buf[atomicAdd(&cnt, 1u)] = s;
        s = sort32(v.z); if ((s >> 20) == sb) buf[atomicAdd(&cnt, 1u)] = s;
        s = sort32(v.w); if ((s >> 20) == sb) buf[atomicAdd(&cnt, 1u)] = s;
    }
    __syncthreads();
    if (threadIdx.x == 0) base = atomicAdd(&extcnt[b], cnt);
    __syncthreads();
    unsigned n = cnt, bs = base;
    for (unsigned i = threadIdx.x; i < n; i += 256) {
        unsigned pos = bs + i;
        if (pos < EXT_CAP) ext[(size_t)b * EXT_CAP + pos] = buf[i];
    }
}

// Resolve remaining 20 bits (12 then 8) among extracted values -> exact thr.
__global__ __launch_bounds__(256) void select23_kernel(const unsigned* __restrict__ ext,
                                                       const unsigned* __restrict__ extcnt,
                                                       const unsigned* __restrict__ selbin,
                                                       const unsigned* __restrict__ k2v,
                                                       float* __restrict__ thr) {
    __shared__ unsigned lh[4096];
    __shared__ unsigned sel2_s, k3_s;
    int b = blockIdx.x, tid = threadIdx.x;
    unsigned m = extcnt[b]; if (m > EXT_CAP) m = EXT_CAP;
    const unsigned* e = ext + (size_t)b * EXT_CAP;

    for (int i = tid; i < 4096; i += 256) lh[i] = 0;
    __syncthreads();
    for (unsigned i = tid; i < m; i += 256) atomicAdd(&lh[(e[i] >> 8) & 0xFFFu], 1u);
    __syncthreads();
    if (tid == 0) {
        unsigned k = k2v[b], c = 0;
        int sel = 0;
        for (int bin = 4095; bin >= 0; --bin) {
            unsigned cnt = lh[bin];
            if (c + cnt >= k) { sel = bin; break; }
            c += cnt;
        }
        sel2_s = (unsigned)sel;
        k3_s   = k - c;
    }
    __syncthreads();
    unsigned sel2 = sel2_s;
    for (int i = tid; i < 256; i += 256) lh[i] = 0;
    __syncthreads();
    for (unsigned i = tid; i < m; i += 256) {
        unsigned s = e[i];
        if (((s >> 8) & 0xFFFu) == sel2) atomicAdd(&lh[s & 0xFFu], 1u);
    }
    __syncthreads();
    if (tid == 0) {
        unsigned k = k3_s, c = 0;
        int sel = 0;
        for (int bin = 255; bin >= 0; --bin) {
            unsigned cnt = lh[bin];
            if (c + cnt >= k) { sel = bin; break; }
            c += cnt;
        }
        unsigned bits = (selbin[b] << 20) | (sel2 << 8) | (unsigned)sel;
        thr[b] = unsort32(bits);
    }
}

// Final: filter candidates by v > thr, top-5 merge, argmax fallback, epilogue.
__global__ __launch_bounds__(256) void final_kernel(const unsigned long long* __restrict__ cands,
                                                    const unsigned* __restrict__ candcnt,
                                                    const unsigned long long* __restrict__ batchmax,
                                                    const float* __restrict__ thr,
                                                    float* __restrict__ out) {
    int b = blockIdx.x, tid = threadIdx.x;
    unsigned n = candcnt[b]; if (n > CAND_CAP) n = CAND_CAP;
    const unsigned long long* cd = cands + (size_t)b * CAND_CAP;
    float th = thr[b];

    unsigned long long t[5] = {0, 0, 0, 0, 0};
    for (unsigned i = tid; i < n; i += 256) {
        unsigned long long key = cd[i];
        float v = unsort32((unsigned)(key >> 32));
        if (v > th) insert5(t, key);
    }

    __shared__ unsigned long long sh5[256 * 5];
#pragma unroll
    for (int k = 0; k < 5; ++k) sh5[tid * 5 + k] = t[k];
    __syncthreads();
    for (int s = 128; s > 0; s >>= 1) {
        if (tid < s) {
            unsigned long long a[5];
#pragma unroll
            for (int k = 0; k < 5; ++k) a[k] = sh5[tid * 5 + k];
            merge5(a, &sh5[(tid + s) * 5]);
#pragma unroll
            for (int k = 0; k < 5; ++k) sh5[tid * 5 + k] = a[k];
        }
        __syncthreads();
    }

    if (tid == 0) {
        float topv[5], xs[5], ys[5];
        bool hp[5];
#pragma unroll
        for (int j = 0; j < 5; ++j) {
            unsigned long long key = sh5[j];
            hp[j] = (key != 0ull);
            if (hp[j]) {
                topv[j] = unsort32((unsigned)(key >> 32));
                unsigned idx = ~((unsigned)key);
                xs[j] = (float)(idx & (W_SZ - 1));
                ys[j] = (float)(idx >> 10);
            } else {
                topv[j] = -INFINITY;
                xs[j] = 0.0f;
                ys[j] = 0.0f;
            }
        }
        if (!hp[0]) {                 // fallback: global argmax (first occurrence)
            unsigned idx = ~((unsigned)batchmax[b]);
            xs[0] = (float)(idx & (W_SZ - 1));
            ys[0] = (float)(idx >> 10);
        }
        float pm = topv[0];
        int nv = 0;
#pragma unroll
        for (int j = 0; j < 5; ++j) {
            bool valid = (topv[j] >= pm * 0.5f) && hp[j];
            nv += valid ? 1 : 0;
        }
        if (nv < 1) nv = 1;
#pragma unroll
        for (int j = 0; j < 5; ++j) {
            bool keep = (j < nv);
            out[b * 10 + j * 2 + 0] = keep ? xs[j] : -1.0f;
            out[b * 10 + j * 2 + 1] = keep ? ys[j] : -1.0f;
            out[160 + b * 5 + j]    = keep ? 1.0f : -1.0f;
        }
    }
}

// ---------- launch ----------

extern "C" void kernel_launch(void* const* d_in, const int* in_sizes, int n_in,
                              void* d_out, int out_size, void* d_ws, size_t ws_size,
                              hipStream_t stream) {
    const float* in = (const float*)d_in[0];
    float* out = (float*)d_out;
    unsigned* w = (unsigned*)d_ws;

    // Zeroed region (contiguous): hist1 | extcnt | candcnt | batchmax
    unsigned* hist1   = w;                                   // 16*4096 = 65536
    unsigned* extcnt  = w + 65536;                           // 16
    unsigned* candcnt = w + 65552;                           // 16
    unsigned long long* batchmax = (unsigned long long*)(w + 65568);  // 16 u64 = 32 words
    // Non-zeroed:
    unsigned* selbin  = w + 65600;                           // 16
    unsigned* k2v     = w + 65616;                           // 16
    float*    thr     = (float*)(w + 65632);                 // 16
    unsigned* ext     = w + 65648;                           // 16*32768 = 524288
    unsigned long long* cands = (unsigned long long*)(w + 65648 + 16 * EXT_CAP); // 16*16384 u64

    zero_kernel<<<257, 256, 0, stream>>>(w, 65600);

    main_kernel<<<8192, 256, 0, stream>>>(in, hist1, cands, candcnt, batchmax);
    selbin_kernel<<<16, 256, 0, stream>>>(hist1, selbin, k2v);
    extract_kernel<<<4096, 256, 0, stream>>>((const unsigned*)in, selbin, ext, extcnt);
    select23_kernel<<<16, 256, 0, stream>>>(ext, extcnt, selbin, k2v, thr);
    final_kernel<<<16, 256, 0, stream>>>(cands, candcnt, batchmax, thr, out);
}

// Round 3
// 314.679 us; speedup vs baseline: 4.5796x; 1.4963x over previous
//
#include <hip/hip_runtime.h>
#include <math.h>

// Problem constants
#define B_SZ   16
#define H_SZ   1024
#define W_SZ   1024
#define K_THR  104857u                 // int((1-0.9)*2^20), rank from top
#define TOPK   5

// Tile geometry for the fused pass
#define TW 64
#define TH 32
#define HALO 4
#define SW (TW + 2*HALO)   // 72 staged width
#define SH (TH + 2*HALO)   // 40 staged height

#define EXT_CAP  32768     // per-batch capacity for selected-bin values (~23k expected)
#define CAND_CAP 16384     // per-batch capacity for local-max candidates (~13k expected)
#define CAND_LDS 128       // per-block candidate staging (expect ~25)

// ---------- helpers ----------

__device__ __forceinline__ unsigned sort32(unsigned u) {
    return (u & 0x80000000u) ? ~u : (u | 0x80000000u);
}
__device__ __forceinline__ float unsort32(unsigned u) {
    unsigned v = (u & 0x80000000u) ? (u & 0x7FFFFFFFu) : ~u;
    return __uint_as_float(v);
}

__device__ __forceinline__ void insert5(unsigned long long t[5], unsigned long long key) {
    if (key <= t[4]) return;
    t[4] = key;
#pragma unroll
    for (int i = 4; i > 0; --i) {
        if (t[i] > t[i - 1]) {
            unsigned long long tmp = t[i - 1];
            t[i - 1] = t[i];
            t[i] = tmp;
        }
    }
}

__device__ __forceinline__ void merge5(unsigned long long a[5], const unsigned long long* b) {
    unsigned long long o[5];
    int i = 0, j = 0;
#pragma unroll
    for (int k = 0; k < 5; ++k) {
        unsigned long long av = a[i], bv = b[j];
        if (av >= bv) { o[k] = av; ++i; } else { o[k] = bv; ++j; }
    }
#pragma unroll
    for (int k = 0; k < 5; ++k) a[k] = o[k];
}

// Parallel block-level top-rank select over a histogram h[NBINS] (LDS or global).
// k is the 1-based rank from the TOP. All 256 threads must call.
// Result: *out_sel = selected bin, *out_c = count strictly above that bin
// (both in LDS, written by exactly one thread). scratch: 256 u32 in LDS.
template <int NBINS>
__device__ __forceinline__ void block_select(const unsigned* h, unsigned k,
                                             unsigned* scratch,
                                             int* out_sel, unsigned* out_c) {
    const int CS = NBINS / 256;
    int t = threadIdx.x;
    unsigned sum = 0;
#pragma unroll
    for (int i = 0; i < CS; ++i) sum += h[t * CS + i];
    scratch[t] = sum;
    __syncthreads();
    // Hillis-Steele inclusive SUFFIX scan: scratch[t] = sum_{j>=t} partial[j]
    for (int d = 1; d < 256; d <<= 1) {
        unsigned v = scratch[t];
        unsigned add = (t + d < 256) ? scratch[t + d] : 0u;
        __syncthreads();
        scratch[t] = v + add;
        __syncthreads();
    }
    unsigned sfx = scratch[t];
    unsigned nxt = (t < 255) ? scratch[t + 1] : 0u;
    if (sfx >= k && nxt < k) {           // unique crossing thread (suffix monotone)
        unsigned c = nxt;
        int sel = t * CS;
        for (int bin = t * CS + CS - 1; bin >= t * CS; --bin) {
            unsigned cnt = h[bin];
            if (c + cnt >= k) { sel = bin; break; }
            c += cnt;
        }
        *out_sel = sel;
        *out_c = c;
    }
    __syncthreads();
}

// ---------- kernels ----------

__global__ __launch_bounds__(256) void zero_kernel(unsigned* p, int n) {
    int i = blockIdx.x * 256 + threadIdx.x;
    if (i < n) p[i] = 0;
}

// Fused single pass: separable 9x9 local-max (candidates), 4096-bin value
// histogram (top 12 bits of sortable float), global argmax key.
// Grid: 16 batches * 512 tiles (16x32 of 64x32) = 8192 blocks, 256 threads.
__global__ __launch_bounds__(256) void main_kernel(const float* __restrict__ in,
                                                   unsigned* __restrict__ hist,
                                                   unsigned long long* __restrict__ cands,
                                                   unsigned* __restrict__ candcnt,
                                                   unsigned long long* __restrict__ batchmax) {
    __shared__ float stile[SH * SW];          // 40x72 staged tile (+halo)
    __shared__ float hbuf[SH * TW];           // 40x64 horizontal 9-max
    __shared__ unsigned lh[4096];             // local histogram
    __shared__ unsigned long long lc[CAND_LDS];
    __shared__ unsigned lcnt, lbase;
    __shared__ unsigned long long wmax[4];

    int bid = blockIdx.x;
    int b   = bid >> 9;                       // batch
    int t   = bid & 511;
    int x0  = (t & 15) << 6;                  // tile origin
    int y0  = (t >> 4) << 5;
    int tid = threadIdx.x;
    const float* img = in + ((size_t)b << 20);

    // Stage tile + halo (out-of-image -> -inf)
    for (int i = tid; i < SH * SW; i += 256) {
        int r = i / SW, c = i % SW;
        int gy = y0 + r - HALO, gx = x0 + c - HALO;
        float v = -INFINITY;
        if ((unsigned)gy < (unsigned)H_SZ && (unsigned)gx < (unsigned)W_SZ)
            v = img[gy * W_SZ + gx];
        stile[i] = v;
    }
    for (int i = tid; i < 4096; i += 256) lh[i] = 0;
    if (tid == 0) lcnt = 0;
    __syncthreads();

    // Horizontal 9-max: 40 rows x 8 runs of 8 outputs = 320 runs.
    for (int run = tid; run < SH * 8; run += 256) {
        int r  = run >> 3;
        int c0 = (run & 7) << 3;
        const float4* p = (const float4*)&stile[r * SW + c0];
        float4 q0 = p[0], q1 = p[1], q2 = p[2], q3 = p[3];
        float a[16] = {q0.x, q0.y, q0.z, q0.w, q1.x, q1.y, q1.z, q1.w,
                       q2.x, q2.y, q2.z, q2.w, q3.x, q3.y, q3.z, q3.w};
        float S[8], P[8];
        S[7] = a[7];
#pragma unroll
        for (int i = 6; i >= 0; --i) S[i] = fmaxf(a[i], S[i + 1]);
        P[0] = a[8];
#pragma unroll
        for (int j = 1; j < 8; ++j) P[j] = fmaxf(P[j - 1], a[8 + j]);
        float o0[8];
#pragma unroll
        for (int o = 0; o < 8; ++o) o0[o] = fmaxf(S[o], P[o]);
        float4* w = (float4*)&hbuf[r * TW + c0];
        w[0] = make_float4(o0[0], o0[1], o0[2], o0[3]);
        w[1] = make_float4(o0[4], o0[5], o0[6], o0[7]);
    }
    __syncthreads();

    // Vertical 9-max + candidate test + histogram + argmax key.
    int c  = tid & 63;
    int r0 = (tid >> 6) << 3;
    float a[16];
#pragma unroll
    for (int i = 0; i < 16; ++i) a[i] = hbuf[(r0 + i) * TW + c];
    float S[8], P[8];
    S[7] = a[7];
#pragma unroll
    for (int i = 6; i >= 0; --i) S[i] = fmaxf(a[i], S[i + 1]);
    P[0] = a[8];
#pragma unroll
    for (int j = 1; j < 8; ++j) P[j] = fmaxf(P[j - 1], a[8 + j]);

    unsigned long long mymax = 0;
#pragma unroll
    for (int o = 0; o < 8; ++o) {
        int ry = r0 + o;
        float vm = fmaxf(S[o], P[o]);
        float v  = stile[(ry + HALO) * SW + (c + HALO)];
        unsigned s = sort32(__float_as_uint(v));
        atomicAdd(&lh[s >> 20], 1u);
        unsigned idx = (unsigned)(((y0 + ry) << 10) | (x0 + c));
        unsigned long long key = ((unsigned long long)s << 32) | (unsigned)(~idx);
        if (key > mymax) mymax = key;
        if (v == vm) {                         // v >= all 80 neighbors
            unsigned p = atomicAdd(&lcnt, 1u);
            if (p < CAND_LDS) lc[p] = key;
        }
    }

    // Wave-level max, then block max -> global atomicMax.
#pragma unroll
    for (int off = 32; off > 0; off >>= 1) {
        unsigned long long o = __shfl_down(mymax, off);
        if (o > mymax) mymax = o;
    }
    if ((tid & 63) == 0) wmax[tid >> 6] = mymax;
    __syncthreads();

    if (tid == 0) {
        unsigned long long m = wmax[0];
        for (int i = 1; i < 4; ++i) if (wmax[i] > m) m = wmax[i];
        atomicMax(&batchmax[b], m);
        unsigned n = lcnt; if (n > CAND_LDS) n = CAND_LDS;
        lbase = atomicAdd(&candcnt[b], n);
    }
    __syncthreads();

    // Flush histogram and candidates.
    unsigned* h = hist + (b << 12);
    for (int i = tid; i < 4096; i += 256) {
        unsigned cc = lh[i];
        if (cc) atomicAdd(&h[i], cc);
    }
    unsigned n = lcnt; if (n > CAND_LDS) n = CAND_LDS;
    unsigned base = lbase;
    for (unsigned i = tid; i < n; i += 256) {
        unsigned pos = base + i;
        if (pos < CAND_CAP) cands[(size_t)b * CAND_CAP + pos] = lc[i];
    }
}

// Level-1 select: per-batch, find 12-bit bin containing rank K_THR from top.
__global__ __launch_bounds__(256) void selbin_kernel(const unsigned* __restrict__ hist,
                                                     unsigned* __restrict__ selbin,
                                                     unsigned* __restrict__ k2v) {
    __shared__ unsigned scratch[256];
    __shared__ int sel_s;
    __shared__ unsigned c_s;
    int b = blockIdx.x;
    const unsigned* h = hist + (b << 12);
    block_select<4096>(h, K_THR, scratch, &sel_s, &c_s);
    if (threadIdx.x == 0) {
        selbin[b] = (unsigned)sel_s;
        k2v[b]    = K_THR - c_s;
    }
}

// Extract all values (sortable bits) whose top-12 bits == selbin, per batch.
__global__ __launch_bounds__(256) void extract_kernel(const unsigned* __restrict__ in,
                                                      const unsigned* __restrict__ selbin,
                                                      unsigned* __restrict__ ext,
                                                      unsigned* __restrict__ extcnt) {
    __shared__ unsigned buf[4096];
    __shared__ unsigned cnt, base;
    int b = blockIdx.x >> 8;
    unsigned sb = selbin[b];
    if (threadIdx.x == 0) cnt = 0;
    __syncthreads();
    size_t blockbase = (size_t)blockIdx.x * 4096;
#pragma unroll
    for (int i = 0; i < 4; ++i) {
        uint4 v = *(const uint4*)(in + blockbase + (size_t)(i * 256 + threadIdx.x) * 4);
        unsigned s;
        s = sort32(v.x); if ((s >> 20) == sb) buf[atomicAdd(&cnt, 1u)] = s;
        s = sort32(v.y); if ((s >> 20) == sb) buf[atomicAdd(&cnt, 1u)] = s;
        s = sort32(v.z); if ((s >> 20) == sb) buf[atomicAdd(&cnt, 1u)] = s;
        s = sort32(v.w); if ((s >> 20) == sb) buf[atomicAdd(&cnt, 1u)] = s;
    }
    __syncthreads();
    if (threadIdx.x == 0) base = atomicAdd(&extcnt[b], cnt);
    __syncthreads();
    unsigned n = cnt, bs = base;
    for (unsigned i = threadIdx.x; i < n; i += 256) {
        unsigned pos = bs + i;
        if (pos < EXT_CAP) ext[(size_t)b * EXT_CAP + pos] = buf[i];
    }
}

// Resolve remaining 20 bits (12 then 8) among extracted values -> exact thr.
__global__ __launch_bounds__(256) void select23_kernel(const unsigned* __restrict__ ext,
                                                       const unsigned* __restrict__ extcnt,
                                                       const unsigned* __restrict__ selbin,
                                                       const unsigned* __restrict__ k2v,
                                                       float* __restrict__ thr) {
    __shared__ unsigned lh[4096];
    __shared__ unsigned scratch[256];
    __shared__ int sel_s;
    __shared__ unsigned c_s;
    int b = blockIdx.x, tid = threadIdx.x;
    unsigned m = extcnt[b]; if (m > EXT_CAP) m = EXT_CAP;
    const unsigned* e = ext + (size_t)b * EXT_CAP;

    // Level 2: middle 12 bits among extracted values.
    for (int i = tid; i < 4096; i += 256) lh[i] = 0;
    __syncthreads();
    for (unsigned i = tid; i < m; i += 256) atomicAdd(&lh[(e[i] >> 8) & 0xFFFu], 1u);
    __syncthreads();
    unsigned k2 = k2v[b];
    block_select<4096>(lh, k2, scratch, &sel_s, &c_s);
    unsigned sel2 = (unsigned)sel_s;
    unsigned k3 = k2 - c_s;
    __syncthreads();                 // everyone read sel_s/c_s before reuse

    // Level 3: low 8 bits among values matching sel2.
    for (int i = tid; i < 256; i += 256) lh[i] = 0;
    __syncthreads();
    for (unsigned i = tid; i < m; i += 256) {
        unsigned s = e[i];
        if (((s >> 8) & 0xFFFu) == sel2) atomicAdd(&lh[s & 0xFFu], 1u);
    }
    __syncthreads();
    block_select<256>(lh, k3, scratch, &sel_s, &c_s);
    if (tid == 0) {
        unsigned bits = (selbin[b] << 20) | (sel2 << 8) | (unsigned)sel_s;
        thr[b] = unsort32(bits);
    }
}

// Final: filter candidates by v > thr, top-5 merge, argmax fallback, epilogue.
__global__ __launch_bounds__(256) void final_kernel(const unsigned long long* __restrict__ cands,
                                                    const unsigned* __restrict__ candcnt,
                                                    const unsigned long long* __restrict__ batchmax,
                                                    const float* __restrict__ thr,
                                                    float* __restrict__ out) {
    int b = blockIdx.x, tid = threadIdx.x;
    unsigned n = candcnt[b]; if (n > CAND_CAP) n = CAND_CAP;
    const unsigned long long* cd = cands + (size_t)b * CAND_CAP;
    float th = thr[b];

    unsigned long long t[5] = {0, 0, 0, 0, 0};
    for (unsigned i = tid; i < n; i += 256) {
        unsigned long long key = cd[i];
        float v = unsort32((unsigned)(key >> 32));
        if (v > th) insert5(t, key);
    }

    __shared__ unsigned long long sh5[256 * 5];
#pragma unroll
    for (int k = 0; k < 5; ++k) sh5[tid * 5 + k] = t[k];
    __syncthreads();
    for (int s = 128; s > 0; s >>= 1) {
        if (tid < s) {
            unsigned long long a[5];
#pragma unroll
            for (int k = 0; k < 5; ++k) a[k] = sh5[tid * 5 + k];
            merge5(a, &sh5[(tid + s) * 5]);
#pragma unroll
            for (int k = 0; k < 5; ++k) sh5[tid * 5 + k] = a[k];
        }
        __syncthreads();
    }

    if (tid == 0) {
        float topv[5], xs[5], ys[5];
        bool hp[5];
#pragma unroll
        for (int j = 0; j < 5; ++j) {
            unsigned long long key = sh5[j];
            hp[j] = (key != 0ull);
            if (hp[j]) {
                topv[j] = unsort32((unsigned)(key >> 32));
                unsigned idx = ~((unsigned)key);
                xs[j] = (float)(idx & (W_SZ - 1));
                ys[j] = (float)(idx >> 10);
            } else {
                topv[j] = -INFINITY;
                xs[j] = 0.0f;
                ys[j] = 0.0f;
            }
        }
        if (!hp[0]) {                 // fallback: global argmax (first occurrence)
            unsigned idx = ~((unsigned)batchmax[b]);
            xs[0] = (float)(idx & (W_SZ - 1));
            ys[0] = (float)(idx >> 10);
        }
        float pm = topv[0];
        int nv = 0;
#pragma unroll
        for (int j = 0; j < 5; ++j) {
            bool valid = (topv[j] >= pm * 0.5f) && hp[j];
            nv += valid ? 1 : 0;
        }
        if (nv < 1) nv = 1;
#pragma unroll
        for (int j = 0; j < 5; ++j) {
            bool keep = (j < nv);
            out[b * 10 + j * 2 + 0] = keep ? xs[j] : -1.0f;
            out[b * 10 + j * 2 + 1] = keep ? ys[j] : -1.0f;
            out[160 + b * 5 + j]    = keep ? 1.0f : -1.0f;
        }
    }
}

// ---------- launch ----------

extern "C" void kernel_launch(void* const* d_in, const int* in_sizes, int n_in,
                              void* d_out, int out_size, void* d_ws, size_t ws_size,
                              hipStream_t stream) {
    const float* in = (const float*)d_in[0];
    float* out = (float*)d_out;
    unsigned* w = (unsigned*)d_ws;

    // Zeroed region (contiguous): hist1 | extcnt | candcnt | batchmax
    unsigned* hist1   = w;                                   // 16*4096 = 65536
    unsigned* extcnt  = w + 65536;                           // 16
    unsigned* candcnt = w + 65552;                           // 16
    unsigned long long* batchmax = (unsigned long long*)(w + 65568);  // 16 u64 = 32 words
    // Non-zeroed:
    unsigned* selbin  = w + 65600;                           // 16
    unsigned* k2v     = w + 65616;                           // 16
    float*    thr     = (float*)(w + 65632);                 // 16
    unsigned* ext     = w + 65648;                           // 16*32768 = 524288
    unsigned long long* cands = (unsigned long long*)(w + 65648 + 16 * EXT_CAP); // 16*16384 u64

    zero_kernel<<<257, 256, 0, stream>>>(w, 65600);

    main_kernel<<<8192, 256, 0, stream>>>(in, hist1, cands, candcnt, batchmax);
    selbin_kernel<<<16, 256, 0, stream>>>(hist1, selbin, k2v);
    extract_kernel<<<4096, 256, 0, stream>>>((const unsigned*)in, selbin, ext, extcnt);
    select23_kernel<<<16, 256, 0, stream>>>(ext, extcnt, selbin, k2v, thr);
    final_kernel<<<16, 256, 0, stream>>>(cands, candcnt, batchmax, thr, out);
}